// Round 20
// baseline (122.949 us; speedup 1.0000x reference)
//
#include <hip/hip_runtime.h>
#include <hip/hip_bf16.h>
#include <math.h>

// BarrierNet fused forward, v18.
// r19->r20: layer-1 moved onto MFMA (K=8 zero-padded to 32). Per wave: 16
// W1 B-frags + 4 x A-frags built in-register (q==0 lanes carry data, q>0
// zero), 64 MFMAs; C-layout -> A-layout via per-wave 16x264-bf16 LDS scratch
// (wave-local s_waitcnt lgkmcnt(0), no barriers). Removes ~2000 VALU FMA +
// 128 VMEM loads + ~18KB straight-line code per thread. Downstream (128KB
// burst stage, MFMA sweep, epilogue, per-thread QP) = r19 verbatim.

typedef unsigned int u32;
typedef unsigned long long u64;
typedef unsigned short u16;
typedef __attribute__((ext_vector_type(8))) short short8;   // 8 bf16 (MFMA A/B)
typedef __attribute__((ext_vector_type(4))) float f32x4;
typedef __attribute__((ext_vector_type(2))) float f32x2;
typedef __attribute__((ext_vector_type(4))) u32 u32x4;

union Frag { short8 v; u32 u[4]; u32x4 q; };

__device__ __forceinline__ u32 packbf(float a, float b) {
    float2 f2; f2.x = a; f2.y = b;
    __hip_bfloat162 h = __float22bfloat162_rn(f2);   // v_cvt_pk_bf16_f32
    union { __hip_bfloat162 h2; u32 u; } cv; cv.h2 = h;
    return cv.u;
}
__device__ __forceinline__ u16 f2bf1(float f) {
    union { float f; u32 i; } v; v.f = f;
    u32 b = v.i;
    return (u16)((b + 0x7fffu + ((b >> 16) & 1u)) >> 16);   // RNE
}

__device__ const float OBX[8] = { 10.f, 7.07106781186547524f, 6.123234e-16f, -7.07106781186547524f,
                                 -10.f, -7.07106781186547524f, -1.8369702e-15f, 7.07106781186547524f };
__device__ const float OBY[8] = { 0.f, 7.07106781186547524f, 10.f, 7.07106781186547524f,
                                  1.2246468e-15f, -7.07106781186547524f, -10.f, -7.07106781186547524f };

// triu_indices(9,1) pairs packed as 4-bit nibbles in u64 immediates
#define PI0_ 0x2111111100000000ULL
#define PI1_ 0x5544443333322222ULL
#define PI2_ 0x7665ULL
#define PJ0_ 0x3876543287654321ULL
#define PJ1_ 0x7687658765487654ULL
#define PJ2_ 0x8878ULL
__device__ __forceinline__ int unpack4(u64 w0, u64 w1, u64 w2, int t) {
    u64 w = (t < 16) ? w0 : (t < 32) ? w1 : w2;
    return (int)((w >> ((t & 15) * 4)) & 15);
}

// ---------- prep: swizzle W2{1,2} (f32 [128][256]) into bf16 B-fragments ----------
__global__ __launch_bounds__(256)
void prep_kernel(const float* __restrict__ W21, const float* __restrict__ W22,
                 u32* __restrict__ ws)
{
    int idx  = blockIdx.x * 256 + threadIdx.x;      // 0..8191
    int lane = idx & 63;
    int nt   = (idx >> 6) & 7;
    int ks   = (idx >> 9) & 7;
    int head = idx >> 12;
    const float* W = head ? W22 : W21;
    int n  = nt * 16 + (lane & 15);
    int k0 = ks * 32 + (lane >> 4) * 8;
    const float* s = W + n * 256 + k0;
    u32x4 o;
    o.x = packbf(s[0], s[1]);
    o.y = packbf(s[2], s[3]);
    o.z = packbf(s[4], s[5]);
    o.w = packbf(s[6], s[7]);
    __builtin_nontemporal_store(o, (u32x4*)ws + idx);
}

// ---------- fused: MFMA layer1 + two MFMA heads + per-thread QP ----------
__global__ __launch_bounds__(256, 1)
void barriernet_kernel(const float* __restrict__ x,      // [B,8]
                       const float* __restrict__ meanp,  // [8]
                       const float* __restrict__ stdp,   // [8]
                       const float* __restrict__ W1,     // [256][8]
                       const float* __restrict__ b1,     // [256]
                       const float* __restrict__ b21,    // [128]
                       const float* __restrict__ W31,    // [2][128]
                       const float* __restrict__ b31,    // [2]
                       const float* __restrict__ b22,    // [128]
                       const float* __restrict__ W32,    // [2][128]
                       const float* __restrict__ b32,    // [2]
                       const u32* __restrict__ wsB,      // swizzled bf16 B-frags
                       float* __restrict__ out, int Btot)
{
    const int tid  = threadIdx.x;
    const int wave = tid >> 6;
    const int lane = tid & 63;
    const int q    = lane >> 4;
    const int m    = lane & 15;
    const int blockRow = blockIdx.x * 256;

    // 128 KB union: hid scratch (33KB) -> B-frag stage (128KB) -> qC (36KB)
    __shared__ u32x4 stage[8192];
    __shared__ float lds_p[256][4];

    // ================= layer-1 via MFMA =================
    // B-frags: W1[n][k], n = nt*16 + m (q==0 lanes), k = j (0..7); q>0 zero.
    Frag w1f[16];
    #pragma unroll
    for (int nt = 0; nt < 16; ++nt) {
        if (q == 0) {
            const f32x4* wv = (const f32x4*)(W1 + (nt * 16 + m) * 8);
            f32x4 w0 = wv[0], w1 = wv[1];
            w1f[nt].u[0] = packbf(w0.x, w0.y);
            w1f[nt].u[1] = packbf(w0.z, w0.w);
            w1f[nt].u[2] = packbf(w1.x, w1.y);
            w1f[nt].u[3] = packbf(w1.z, w1.w);
        } else {
            w1f[nt].u[0] = 0; w1f[nt].u[1] = 0; w1f[nt].u[2] = 0; w1f[nt].u[3] = 0;
        }
    }
    float b1c[16];
    #pragma unroll
    for (int nt = 0; nt < 16; ++nt) b1c[nt] = b1[nt * 16 + m];

    // A-frags: x[row][k], row = mt*16 + m (q==0 lanes); q>0 zero.
    Frag xf[4];
    #pragma unroll
    for (int mt = 0; mt < 4; ++mt) {
        if (q == 0) {
            int R0 = blockRow + wave * 64 + mt * 16 + m;
            const f32x4* xv = (const f32x4*)(x + (R0 < Btot ? R0 : 0) * 8);
            f32x4 x0 = xv[0], x1 = xv[1];
            xf[mt].u[0] = packbf(x0.x, x0.y);
            xf[mt].u[1] = packbf(x0.z, x0.w);
            xf[mt].u[2] = packbf(x1.x, x1.y);
            xf[mt].u[3] = packbf(x1.z, x1.w);
        } else {
            xf[mt].u[0] = 0; xf[mt].u[1] = 0; xf[mt].u[2] = 0; xf[mt].u[3] = 0;
        }
    }

    // per-wave hid scratch: 16 rows x 264 bf16 (row stride 528B, 16B-aligned)
    u16* hidw = (u16*)stage + wave * (16 * 264);
    Frag A[4][8];
    #pragma unroll
    for (int mt = 0; mt < 4; ++mt) {
        #pragma unroll
        for (int nt = 0; nt < 16; ++nt) {
            f32x4 c = __builtin_amdgcn_mfma_f32_16x16x32_bf16(
                xf[mt].v, w1f[nt].v, (f32x4){0.f, 0.f, 0.f, 0.f}, 0, 0, 0);
            // C-layout: lane holds rows q*4+rg (local), col nt*16+m
            #pragma unroll
            for (int rg = 0; rg < 4; ++rg) {
                float v = fmaxf(c[rg] + b1c[nt], 0.f);
                hidw[(q * 4 + rg) * 264 + nt * 16 + m] = f2bf1(v);
            }
        }
        asm volatile("s_waitcnt lgkmcnt(0)" ::: "memory");   // writes visible wave-wide
        #pragma unroll
        for (int ks = 0; ks < 8; ++ks)
            A[mt][ks].q = *(const u32x4*)(hidw + m * 264 + ks * 32 + q * 8);
        asm volatile("s_waitcnt lgkmcnt(0)" ::: "memory");   // reads done before overwrite
    }
    __syncthreads();   // all waves done with hid scratch before burst overwrites

    // ================= stage ALL W2 B-frags (128 KB), one barrier =================
    const u32x4* wsB4 = (const u32x4*)wsB;
    #pragma unroll
    for (int i = 0; i < 32; ++i) {
        int fi = i * 256 + tid;
        stage[fi] = wsB4[fi];
    }
    __syncthreads();

    #pragma unroll 1
    for (int head = 0; head < 2; ++head) {
        const float* b2 = head ? b22 : b21;
        const float* W3 = head ? W32 : W31;
        const float* b3 = head ? b32 : b31;

        f32x4 acc[4][8];
        #pragma unroll
        for (int mt = 0; mt < 4; ++mt)
            #pragma unroll
            for (int nt = 0; nt < 8; ++nt) acc[mt][nt] = (f32x4){0.f, 0.f, 0.f, 0.f};

        #pragma unroll
        for (int ks = 0; ks < 8; ++ks) {
            Frag Bf[8];
            #pragma unroll
            for (int nt = 0; nt < 8; ++nt)
                Bf[nt].q = stage[head * 4096 + ks * 512 + nt * 64 + lane];
            #pragma unroll
            for (int nt = 0; nt < 8; ++nt) {
                #pragma unroll
                for (int mt = 0; mt < 4; ++mt)
                    acc[mt][nt] = __builtin_amdgcn_mfma_f32_16x16x32_bf16(
                        A[mt][ks].v, Bf[nt].v, acc[mt][nt], 0, 0, 0);
            }
        }

        // ---- epilogue: bias+relu+W3 dot, 16-lane reduce, LDS scatter
        float pr0[4][4], pr1[4][4];
        #pragma unroll
        for (int mt = 0; mt < 4; ++mt)
            #pragma unroll
            for (int rg = 0; rg < 4; ++rg) { pr0[mt][rg] = 0.f; pr1[mt][rg] = 0.f; }
        #pragma unroll
        for (int nt = 0; nt < 8; ++nt) {
            int col = nt * 16 + m;
            float b2c = b2[col];
            float w0c = W3[col];
            float w1c = W3[128 + col];
            #pragma unroll
            for (int mt = 0; mt < 4; ++mt) {
                #pragma unroll
                for (int rg = 0; rg < 4; ++rg) {
                    float rv = fmaxf(acc[mt][nt][rg] + b2c, 0.f);
                    pr0[mt][rg] = fmaf(rv, w0c, pr0[mt][rg]);
                    pr1[mt][rg] = fmaf(rv, w1c, pr1[mt][rg]);
                }
            }
        }
        #pragma unroll
        for (int mt = 0; mt < 4; ++mt) {
            #pragma unroll
            for (int rg = 0; rg < 4; ++rg) {
                float v0 = pr0[mt][rg], v1 = pr1[mt][rg];
                #pragma unroll
                for (int off = 1; off < 16; off <<= 1) {
                    v0 += __shfl_xor(v0, off, 64);
                    v1 += __shfl_xor(v1, off, 64);
                }
                pr0[mt][rg] = v0; pr1[mt][rg] = v1;
            }
        }
        if (m == 0) {
            #pragma unroll
            for (int mt = 0; mt < 4; ++mt) {
                #pragma unroll
                for (int rg = 0; rg < 4; ++rg) {
                    int row = wave * 64 + mt * 16 + q * 4 + rg;
                    float a0 = pr0[mt][rg] + b3[0];
                    float a1 = pr1[mt][rg] + b3[1];
                    if (head == 0) {
                        lds_p[row][0] = a0;
                        lds_p[row][1] = a1;
                    } else {
                        lds_p[row][2] = 4.f / (1.f + __expf(-a0));
                        lds_p[row][3] = 4.f / (1.f + __expf(-a1));
                    }
                }
            }
        }
    }
    __syncthreads();   // lds_p visible; stage reads done (qC aliasing safe)

    // ================= QP: one thread per row, no merge =================
    f32x4 (*qC)[256] = (f32x4(*)[256])stage;   // 36 KB of the 128 KB region

    const int R = blockRow + tid;
    float p0 = lds_p[tid][0];
    float p1 = lds_p[tid][1];
    {
        float s0 = lds_p[tid][2];
        float s1 = lds_p[tid][3];
        float xr[8];
        const float* xp = x + (R < Btot ? R : 0) * 8;
        #pragma unroll
        for (int c = 0; c < 8; ++c) xr[c] = fmaf(xp[c], stdp[c], meanp[c]);
        float px = xr[0], py = xr[1], th = xr[2], v = xr[3];
        float ox = xr[4], oy = xr[5], oth = xr[6], ov = xr[7];
        float st = __sinf(th),  ct = __cosf(th);
        float so = __sinf(oth), co = __cosf(oth);
        float vs = v * st, vc = v * ct;
        float sps = s0 + s1, ss = s0 * s1;
        float Lf2b = 2.f * v * v;
        #pragma unroll 1
        for (int k = 0; k < 8; ++k) {
            float dx = px - OBX[k], dy = py - OBY[k];
            float bar  = dx * dx + dy * dy - 0.64f;
            float bdot = 2.f * dx * vc + 2.f * dy * vs;
            float gx = 2.f * dx * vs - 2.f * dy * vc;
            float gy = -(2.f * dx * ct + 2.f * dy * st);
            float hk = Lf2b + sps * bdot + ss * bar;
            float ht = hk + 1e-6f * (1.f + fabsf(hk));
            qC[k][tid] = (f32x4){gx, gy, hk, ht};
        }
        {
            float dxo = px - ox, dyo = py - oy;
            float bar_o  = dxo * dxo + dyo * dyo - 0.25f;
            float bdot_o = 2.f * dxo * (vc - ov * co) + 2.f * dyo * (vs - ov * so);
            float Lf2b_o = 2.f * (v * v + ov * ov + 2.f * v * ov * __cosf(th - oth));
            float gx = 2.f * dxo * vs - 2.f * dyo * vc;
            float gy = -(2.f * dxo * ct + 2.f * dyo * st);
            float hk = Lf2b_o + sps * bdot_o + ss * bar_o;
            float ht = hk + 1e-6f * (1.f + fabsf(hk));
            qC[8][tid] = (f32x4){gx, gy, hk, ht};
        }
    }
    // own-column data: each thread reads only what it wrote (no barrier)
    const f32x4 C0 = qC[0][tid], C1 = qC[1][tid], C2 = qC[2][tid];
    const f32x4 C3 = qC[3][tid], C4 = qC[4][tid], C5 = qC[5][tid];
    const f32x4 C6 = qC[6][tid], C7 = qC[7][tid], C8 = qC[8][tid];

    float bobj = INFINITY;
    float bzx = -p0, bzy = -p1;     // argmin of all-inf -> index 0 -> z0
    #pragma unroll 2
    for (int c = 0; c < 46; ++c) {
        float zx, zy;
        bool pre;
        if (c == 0) {
            zx = -p0; zy = -p1; pre = true;
        } else if (c <= 9) {
            f32x4 g = qC[c - 1][tid];                // one ds_read_b128
            float gg  = g.x * g.x + g.y * g.y;
            float lam = (-(g.x * p0 + g.y * p1) - g.z) / (gg + 1e-12f);
            zx = -p0 - lam * g.x;
            zy = -p1 - lam * g.y;
            pre = (lam >= -1e-8f);
        } else {
            int t = c - 10;
            int pi = unpack4(PI0_, PI1_, PI2_, t);   // scalar, no memory
            int pj = unpack4(PJ0_, PJ1_, PJ2_, t);
            f32x4 gi = qC[pi][tid];                  // two ds_read_b128
            f32x4 gj = qC[pj][tid];
            float det = gi.x * gj.y - gi.y * gj.x;
            bool dok = fabsf(det) > 1e-9f;
            float ds = dok ? det : 1.0f;
            float inv = 1.0f / ds;
            zx = (gi.z * gj.y - gj.z * gi.y) * inv;
            zy = (gi.x * gj.z - gj.x * gi.z) * inv;
            float rx = -(zx + p0), ry = -(zy + p1);
            float li = (gj.y * rx - gj.x * ry) * inv;
            float lj = (gi.x * ry - gi.y * rx) * inv;
            pre = dok && (li >= -1e-8f) && (lj >= -1e-8f);
        }
        bool ok = pre;
        ok = ok && (zx * C0.x + zy * C0.y <= C0.w);
        ok = ok && (zx * C1.x + zy * C1.y <= C1.w);
        ok = ok && (zx * C2.x + zy * C2.y <= C2.w);
        ok = ok && (zx * C3.x + zy * C3.y <= C3.w);
        ok = ok && (zx * C4.x + zy * C4.y <= C4.w);
        ok = ok && (zx * C5.x + zy * C5.y <= C5.w);
        ok = ok && (zx * C6.x + zy * C6.y <= C6.w);
        ok = ok && (zx * C7.x + zy * C7.y <= C7.w);
        ok = ok && (zx * C8.x + zy * C8.y <= C8.w);
        float obj = 0.5f * (zx * zx + zy * zy) + zx * p0 + zy * p1;
        if (ok && obj < bobj) { bobj = obj; bzx = zx; bzy = zy; }
    }

    if (R < Btot) {
        f32x2 o2; o2.x = bzx; o2.y = bzy;
        ((f32x2*)out)[R] = o2;
    }
}

extern "C" void kernel_launch(void* const* d_in, const int* in_sizes, int n_in,
                              void* d_out, int out_size, void* d_ws, size_t ws_size,
                              hipStream_t stream) {
    const float* x    = (const float*)d_in[0];
    const float* mean = (const float*)d_in[1];
    const float* stdv = (const float*)d_in[2];
    const float* W1   = (const float*)d_in[3];
    const float* b1   = (const float*)d_in[4];
    const float* W21  = (const float*)d_in[5];
    const float* b21  = (const float*)d_in[6];
    const float* W31  = (const float*)d_in[7];
    const float* b31  = (const float*)d_in[8];
    const float* W22  = (const float*)d_in[9];
    const float* b22  = (const float*)d_in[10];
    const float* W32  = (const float*)d_in[11];
    const float* b32  = (const float*)d_in[12];
    int B = in_sizes[0] / 8;
    float* out = (float*)d_out;
    u32* ws = (u32*)d_ws;

    hipLaunchKernelGGL(prep_kernel, dim3(32), dim3(256), 0, stream, W21, W22, ws);

    hipLaunchKernelGGL(barriernet_kernel, dim3((B + 255) / 256), dim3(256), 0, stream,
                       x, mean, stdv, W1, b1, b21, W31, b31, b22, W32, b32,
                       ws, out, B);
}